// Round 6
// baseline (1723.704 us; speedup 1.0000x reference)
//
#include <hip/hip_runtime.h>
#include <hip/hip_bf16.h>

#define N_NODES 100000
#define N_EDGES 1600000
#define IN_DIM 128
#define HID_DIM 256
#define OUT_DIM 128

typedef unsigned long long ull;

__device__ __forceinline__ float bf2f(unsigned short u) {
  union { unsigned int i; float f; } c; c.i = ((unsigned int)u) << 16; return c.f;
}
__device__ __forceinline__ unsigned short f2bf(float f) {
  __hip_bfloat16 h = __float2bfloat16(f);
  return *(unsigned short*)&h;
}

__global__ void zero_kernel(int* p, int n) {
  int i = blockIdx.x * 256 + threadIdx.x;
  if (i < n) p[i] = 0;
}

// flags[0] = emode (1 = edge_index int64, 0 = int32)
// flags[1] = fmode (1 = floats fp32, 0 = bf16) — R3 vs R4 behavior proved fp32.
__global__ void detect_kernel(const int* __restrict__ ei,
                              const unsigned int* __restrict__ xw,
                              int* __restrict__ flags) {
  if (blockIdx.x == 0 && threadIdx.x == 0) {
    const long long* p = (const long long*)ei;
    int ok64 = 1;
    for (int i = 0; i < 16; ++i) {
      long long v = p[i];
      if (v < 0 || v >= N_NODES) ok64 = 0;
    }
    flags[0] = ok64;
    int isf32 = 0;
    for (int i = 0; i < 256; ++i) {
      unsigned int e = (xw[i] >> 7) & 0xFF;  // exponent of low-half bf16 view
      if (e >= 0xC0) isf32 = 1;              // |v| >= 2^65 impossible for real data
    }
    flags[1] = isf32;
  }
}

__device__ __forceinline__ int edge_at(const int* ei, int idx, int mode) {
  return mode ? (int)((const long long*)ei)[idx] : ei[idx];
}

__global__ void count_kernel(const int* __restrict__ ei, const int* __restrict__ flags,
                             int* __restrict__ deg) {
  int e = blockIdx.x * 256 + threadIdx.x;
  if (e >= N_EDGES) return;
  int m = flags[0];
  unsigned d = (unsigned)edge_at(ei, N_EDGES + e, m);
  if (d < N_NODES) atomicAdd(&deg[d], 1);
}

// Single-wave serial-chunk exclusive scan: lane L owns rows [L*C,(L+1)*C).
__global__ void scan_kernel(const int* __restrict__ deg, int* __restrict__ off,
                            int* __restrict__ cur, float* __restrict__ dinv, int n) {
  int lane = threadIdx.x;            // blockDim = 64
  int C = (n + 63) >> 6;
  int lo = lane * C;
  int hi = lo + C; if (hi > n) hi = n;
  int s = 0;
  for (int i = lo; i < hi; ++i) s += deg[i];
  int x = s;
  #pragma unroll
  for (int o = 1; o < 64; o <<= 1) {
    int y = __shfl_up(x, o);
    if (lane >= o) x += y;
  }
  int run = x - s;                   // exclusive prefix of this chunk
  for (int i = lo; i < hi; ++i) {
    int v = deg[i];
    off[i] = run;
    cur[i] = run;
    dinv[i] = rsqrtf((float)(v + 1));  // +1 self-loop
    run += v;
  }
  if (lane == 63) off[n] = x;
}

__global__ void fill_kernel(const int* __restrict__ ei, const int* __restrict__ flags,
                            int* __restrict__ cur, int* __restrict__ csr) {
  int e = blockIdx.x * 256 + threadIdx.x;
  if (e >= N_EDGES) return;
  int m = flags[0];
  int s = edge_at(ei, e, m);
  unsigned d = (unsigned)edge_at(ei, N_EDGES + e, m);
  if (d < N_NODES) {
    int p = atomicAdd(&cur[d], 1);
    if ((unsigned)p < N_EDGES) csr[p] = s;
  }
}

// W:[K][N] (fp32 or bf16 per fmode) -> Wt:[N][K] bf16.
__global__ void transpose_kernel(const void* __restrict__ W, const int* __restrict__ flags,
                                 unsigned short* __restrict__ Wt, int K, int N) {
  int i = blockIdx.x * 256 + threadIdx.x;
  if (i >= K * N) return;
  int k = i / N, n = i % N;
  unsigned short v = flags[1] ? f2bf(((const float*)W)[i]) : ((const unsigned short*)W)[i];
  Wt[n * K + k] = v;
}

__global__ void convb_kernel(const void* __restrict__ b, const int* __restrict__ flags,
                             unsigned short* __restrict__ bc, int n) {
  int i = blockIdx.x * 256 + threadIdx.x;
  if (i >= n) return;
  bc[i] = flags[1] ? f2bf(((const float*)b)[i]) : ((const unsigned short*)b)[i];
}

// One wave per node, width 128:
//   out[d] = dinv[d]*(dinv[d]*V[d] + sum_{s in CSR[d]} dinv[s]*V[s]) [+ bias].
// RAWIN: V is fp32 per flags[1] (x input). OUTF32: store fp32 (d_out contract)
// else packed bf16.
template <bool BIAS, bool RAWIN, bool OUTF32>
__global__ __launch_bounds__(256) void agg_kernel(
    const void* __restrict__ Vv, const int* __restrict__ off, const int* __restrict__ csr,
    const float* __restrict__ dinv, const unsigned short* __restrict__ bias,
    const int* __restrict__ flags, void* __restrict__ outv) {
  int d = (blockIdx.x * 256 + threadIdx.x) >> 6;
  int lane = threadIdx.x & 63;
  if (d >= N_NODES) return;
  bool f32 = RAWIN && (flags[1] != 0);
  const float* Vf = (const float*)Vv;
  const unsigned short* Vh = (const unsigned short*)Vv;
  float dv = dinv[d];
  float a0, a1;
  if (f32) {
    a0 = dv * Vf[(size_t)d * 128 + lane * 2];
    a1 = dv * Vf[(size_t)d * 128 + lane * 2 + 1];
  } else {
    unsigned int w = *(const unsigned int*)(Vh + (size_t)d * 128 + lane * 2);
    a0 = dv * bf2f((unsigned short)w);
    a1 = dv * bf2f((unsigned short)(w >> 16));
  }
  int e1 = off[d + 1];
  for (int e = off[d]; e < e1; ++e) {
    int s = csr[e];
    float ds = dinv[s];
    if (f32) {
      a0 = fmaf(ds, Vf[(size_t)s * 128 + lane * 2], a0);
      a1 = fmaf(ds, Vf[(size_t)s * 128 + lane * 2 + 1], a1);
    } else {
      unsigned int w = *(const unsigned int*)(Vh + (size_t)s * 128 + lane * 2);
      a0 = fmaf(ds, bf2f((unsigned short)w), a0);
      a1 = fmaf(ds, bf2f((unsigned short)(w >> 16)), a1);
    }
  }
  a0 *= dv; a1 *= dv;
  if (BIAS) {
    a0 += bf2f(bias[lane * 2]);
    a1 += bf2f(bias[lane * 2 + 1]);
  }
  size_t idx = (size_t)d * 128 + lane * 2;
  if (OUTF32) {
    float* of = (float*)outv;
    of[idx] = a0;
    of[idx + 1] = a1;
  } else {
    unsigned int wo = (unsigned int)f2bf(a0) | ((unsigned int)f2bf(a1) << 16);
    *(unsigned int*)((unsigned short*)outv + idx) = wo;
  }
}

enum { E_BIASRELU = 0, E_WRITE = 1, E_ACCUM = 2 };

// Plain VALU fp32-FMA GEMM (layout-trivial): C[m][0..127] (+)= A[m][:128] . Wt[n][:128].
// Wave = 4 rows x 128 cols; lane handles cols {lane, lane+64}.
template <int SB, int EPI>
__global__ __launch_bounds__(256) void vgemm_kernel(
    const unsigned short* __restrict__ A,   // [M][128] bf16
    const unsigned short* __restrict__ Wt,  // [out rows][SB] bf16 (slice pre-offset)
    const unsigned short* __restrict__ bias,
    unsigned short* __restrict__ C, int M) {
  constexpr int K = 128;
  int wid = threadIdx.x >> 6, lane = threadIdx.x & 63;
  int m0 = (blockIdx.x * 4 + wid) * 4;
  if (m0 >= M) return;
  const unsigned short* Ar = A + (size_t)m0 * K;
  const unsigned short* B0 = Wt + (size_t)lane * SB;
  const unsigned short* B1 = Wt + (size_t)(lane + 64) * SB;
  float acc[4][2] = {};
  for (int k = 0; k < K; k += 4) {
    ull b0 = *(const ull*)(B0 + k);
    ull b1 = *(const ull*)(B1 + k);
    #pragma unroll
    for (int r = 0; r < 4; ++r) {
      ull aw = *(const ull*)(Ar + (size_t)r * K + k);
      #pragma unroll
      for (int j = 0; j < 4; ++j) {
        float av = bf2f((unsigned short)(aw >> (16 * j)));
        acc[r][0] = fmaf(av, bf2f((unsigned short)(b0 >> (16 * j))), acc[r][0]);
        acc[r][1] = fmaf(av, bf2f((unsigned short)(b1 >> (16 * j))), acc[r][1]);
      }
    }
  }
  #pragma unroll
  for (int r = 0; r < 4; ++r) {
    int m = m0 + r;
    if (m >= M) break;
    size_t i0 = (size_t)m * 128 + lane;
    float v0 = acc[r][0], v1 = acc[r][1];
    if (EPI == E_BIASRELU) {
      v0 = fmaxf(v0 + bf2f(bias[lane]), 0.0f);
      v1 = fmaxf(v1 + bf2f(bias[lane + 64]), 0.0f);
    } else if (EPI == E_ACCUM) {
      v0 += bf2f(C[i0]);
      v1 += bf2f(C[i0 + 64]);
    }
    C[i0] = f2bf(v0);
    C[i0 + 64] = f2bf(v1);
  }
}

extern "C" void kernel_launch(void* const* d_in, const int* in_sizes, int n_in,
                              void* d_out, int out_size, void* d_ws, size_t ws_size,
                              hipStream_t stream) {
  const void* x  = d_in[0];
  const int*  ei = (const int*)d_in[1];
  const void* W1 = d_in[2];
  const void* b1 = d_in[3];
  const void* W2 = d_in[4];
  const void* b2 = d_in[5];

  // Workspace carve — total ~59.4 MB
  char* wsb = (char*)d_ws;
  size_t o = 0;
  auto carve = [&](size_t bytes) {
    o = (o + 511) & ~(size_t)511;
    void* p = wsb + o;
    o += bytes;
    return p;
  };
  int*   flags = (int*)carve(8);
  int*   deg  = (int*)carve((size_t)N_NODES * 4);
  int*   off  = (int*)carve((size_t)(N_NODES + 1) * 4);
  int*   cur  = (int*)carve((size_t)N_NODES * 4);
  float* dinv = (float*)carve((size_t)N_NODES * 4);
  int*   csr  = (int*)carve((size_t)N_EDGES * 4);
  unsigned short* Wt1 = (unsigned short*)carve((size_t)IN_DIM * HID_DIM * 2);   // [256][128]
  unsigned short* Wt2 = (unsigned short*)carve((size_t)HID_DIM * OUT_DIM * 2);  // [128][256]
  unsigned short* b1c = (unsigned short*)carve((size_t)HID_DIM * 2);
  unsigned short* b2c = (unsigned short*)carve((size_t)OUT_DIM * 2);
  unsigned short* hh  = (unsigned short*)carve((size_t)N_NODES * 128 * 2);  // h half [N,128]
  unsigned short* g2  = (unsigned short*)carve((size_t)N_NODES * 128 * 2);  // h@W2   [N,128]
  unsigned short* xa  = (unsigned short*)d_out;  // bf16 scratch inside fp32 d_out (25.6/51.2 MB)

  detect_kernel<<<1, 64, 0, stream>>>(ei, (const unsigned int*)x, flags);
  zero_kernel<<<(N_NODES + 255) / 256, 256, 0, stream>>>(deg, N_NODES);
  count_kernel<<<(N_EDGES + 255) / 256, 256, 0, stream>>>(ei, flags, deg);
  scan_kernel<<<1, 64, 0, stream>>>(deg, off, cur, dinv, N_NODES);
  fill_kernel<<<(N_EDGES + 255) / 256, 256, 0, stream>>>(ei, flags, cur, csr);
  transpose_kernel<<<(IN_DIM * HID_DIM + 255) / 256, 256, 0, stream>>>(W1, flags, Wt1, IN_DIM, HID_DIM);
  transpose_kernel<<<(HID_DIM * OUT_DIM + 255) / 256, 256, 0, stream>>>(W2, flags, Wt2, HID_DIM, OUT_DIM);
  convb_kernel<<<1, 256, 0, stream>>>(b1, flags, b1c, HID_DIM);
  convb_kernel<<<1, 256, 0, stream>>>(b2, flags, b2c, OUT_DIM);

  // xa = Ahat @ x   (aggregate-first: Ahat(x W1) == (Ahat x) W1; reads raw fp32 x, bf16 out)
  agg_kernel<false, true, false>
      <<<(N_NODES * 64) / 256, 256, 0, stream>>>(x, off, csr, dinv, nullptr, flags, xa);

  int ggrid = (N_NODES + 15) / 16;
  // half 0: hh = relu(xa @ W1[:,0:128] + b1[0:128]);  g2  = hh @ W2[0:128,:]
  vgemm_kernel<128, E_BIASRELU><<<ggrid, 256, 0, stream>>>(xa, Wt1, b1c, hh, N_NODES);
  vgemm_kernel<256, E_WRITE><<<ggrid, 256, 0, stream>>>(hh, Wt2, nullptr, g2, N_NODES);
  // half 1: hh = relu(xa @ W1[:,128:256] + b1[128:256]);  g2 += hh @ W2[128:256,:]
  vgemm_kernel<128, E_BIASRELU><<<ggrid, 256, 0, stream>>>(xa, Wt1 + 128 * 128, b1c + 128, hh, N_NODES);
  vgemm_kernel<256, E_ACCUM><<<ggrid, 256, 0, stream>>>(hh, Wt2 + 128, nullptr, g2, N_NODES);

  // out = Ahat @ g2 + b2   — fp32 store (d_out is float*: reference output dtype)
  agg_kernel<true, false, true>
      <<<(N_NODES * 64) / 256, 256, 0, stream>>>(g2, off, csr, dinv, b2c, flags, d_out);
}

// Round 7
// 747.677 us; speedup vs baseline: 2.3054x; 2.3054x over previous
//
#include <hip/hip_runtime.h>
#include <hip/hip_bf16.h>

#define N_NODES 100000
#define N_EDGES 1600000
#define IN_DIM 128
#define HID_DIM 256
#define OUT_DIM 128
#define HPAD 264  // LDS row stride (elements) for 256-wide hh tile
#define NB ((N_NODES + 1023) / 1024)  // 98 scan blocks

typedef __attribute__((ext_vector_type(8))) short bf16x8;
typedef __attribute__((ext_vector_type(4))) float f32x4;
typedef __attribute__((ext_vector_type(4))) float float4v;
typedef unsigned long long ull;

__device__ __forceinline__ float bf2f(unsigned short u) {
  union { unsigned int i; float f; } c; c.i = ((unsigned int)u) << 16; return c.f;
}
__device__ __forceinline__ unsigned short f2bf(float f) {
  __hip_bfloat16 h = __float2bfloat16(f);
  return *(unsigned short*)&h;
}

__global__ void zero_kernel(int* p, int n) {
  int i = blockIdx.x * 256 + threadIdx.x;
  if (i < n) p[i] = 0;
}

// flags[0] = emode (1 = edge_index int64), flags[1] = fmode (1 = floats fp32).
__global__ void detect_kernel(const int* __restrict__ ei,
                              const unsigned int* __restrict__ xw,
                              int* __restrict__ flags) {
  if (blockIdx.x == 0 && threadIdx.x == 0) {
    const long long* p = (const long long*)ei;
    int ok64 = 1;
    for (int i = 0; i < 16; ++i) {
      long long v = p[i];
      if (v < 0 || v >= N_NODES) ok64 = 0;
    }
    flags[0] = ok64;
    int isf32 = 0;
    for (int i = 0; i < 256; ++i) {
      unsigned int e = (xw[i] >> 7) & 0xFF;
      if (e >= 0xC0) isf32 = 1;  // |v| >= 2^65: impossible for real data
    }
    flags[1] = isf32;
  }
}

__device__ __forceinline__ int edge_at(const int* ei, int idx, int mode) {
  return mode ? (int)((const long long*)ei)[idx] : ei[idx];
}

__global__ void count_kernel(const int* __restrict__ ei, const int* __restrict__ flags,
                             int* __restrict__ deg) {
  int e = blockIdx.x * 256 + threadIdx.x;
  if (e >= N_EDGES) return;
  int m = flags[0];
  unsigned d = (unsigned)edge_at(ei, N_EDGES + e, m);
  if (d < N_NODES) atomicAdd(&deg[d], 1);
}

// --- hierarchical scan (R6's single-wave scan was 527 us, latency-bound) ---
__global__ __launch_bounds__(1024) void bsum_kernel(const int* __restrict__ deg,
                                                    int* __restrict__ bsum, int n) {
  __shared__ int ws[16];
  int tid = threadIdx.x, lane = tid & 63, wid = tid >> 6;
  int idx = blockIdx.x * 1024 + tid;
  int v = (idx < n) ? deg[idx] : 0;
  #pragma unroll
  for (int o = 32; o > 0; o >>= 1) v += __shfl_down(v, o);
  if (lane == 0) ws[wid] = v;
  __syncthreads();
  if (tid == 0) {
    int r = 0;
    #pragma unroll
    for (int i = 0; i < 16; ++i) r += ws[i];
    bsum[blockIdx.x] = r;
  }
}

__global__ void bscan_kernel(const int* __restrict__ bsum, int* __restrict__ boff,
                             int* __restrict__ total, int nb) {
  int lane = threadIdx.x;  // blockDim = 64
  int carry = 0;
  for (int c = 0; c < (nb + 63) / 64; ++c) {
    int idx = c * 64 + lane;
    int v = (idx < nb) ? bsum[idx] : 0;
    int x = v;
    #pragma unroll
    for (int o = 1; o < 64; o <<= 1) {
      int y = __shfl_up(x, o);
      if (lane >= o) x += y;
    }
    if (idx < nb) boff[idx] = carry + x - v;
    carry += __shfl(x, 63);
  }
  if (lane == 0) *total = carry;
}

__global__ __launch_bounds__(1024) void bfill_kernel(const int* __restrict__ deg,
                                                     const int* __restrict__ boff,
                                                     int* __restrict__ off,
                                                     int* __restrict__ cur,
                                                     float* __restrict__ dinv, int n) {
  __shared__ int wsum[16];
  __shared__ int wpre[16];
  int tid = threadIdx.x, lane = tid & 63, wid = tid >> 6;
  int idx = blockIdx.x * 1024 + tid;
  int v = (idx < n) ? deg[idx] : 0;
  int x = v;
  #pragma unroll
  for (int o = 1; o < 64; o <<= 1) {
    int y = __shfl_up(x, o);
    if (lane >= o) x += y;
  }
  if (lane == 63) wsum[wid] = x;
  __syncthreads();
  if (tid == 0) {
    int r = 0;
    #pragma unroll
    for (int i = 0; i < 16; ++i) { wpre[i] = r; r += wsum[i]; }
  }
  __syncthreads();
  int excl = boff[blockIdx.x] + wpre[wid] + x - v;
  if (idx < n) {
    off[idx] = excl;
    cur[idx] = excl;
    dinv[idx] = rsqrtf((float)(v + 1));  // +1 self-loop
  }
}

__global__ void fill_kernel(const int* __restrict__ ei, const int* __restrict__ flags,
                            int* __restrict__ cur, int* __restrict__ csr) {
  int e = blockIdx.x * 256 + threadIdx.x;
  if (e >= N_EDGES) return;
  int m = flags[0];
  int s = edge_at(ei, e, m);
  unsigned d = (unsigned)edge_at(ei, N_EDGES + e, m);
  if (d < N_NODES) {
    int p = atomicAdd(&cur[d], 1);
    if ((unsigned)p < N_EDGES) csr[p] = s;
  }
}

// W:[K][N] (fp32 or bf16 per fmode) -> Wt:[N][K] bf16.
__global__ void transpose_kernel(const void* __restrict__ W, const int* __restrict__ flags,
                                 unsigned short* __restrict__ Wt, int K, int N) {
  int i = blockIdx.x * 256 + threadIdx.x;
  if (i >= K * N) return;
  int k = i / N, n = i % N;
  unsigned short v = flags[1] ? f2bf(((const float*)W)[i]) : ((const unsigned short*)W)[i];
  Wt[n * K + k] = v;
}

__global__ void convb_kernel(const void* __restrict__ b, const int* __restrict__ flags,
                             unsigned short* __restrict__ bc, int n) {
  int i = blockIdx.x * 256 + threadIdx.x;
  if (i >= n) return;
  bc[i] = flags[1] ? f2bf(((const float*)b)[i]) : ((const unsigned short*)b)[i];
}

// x (fp32 or bf16) -> xc bf16, 4 elem/thread. Halves gather traffic in agg1.
__global__ void convx_kernel(const void* __restrict__ x, const int* __restrict__ flags,
                             unsigned short* __restrict__ xc, int n4) {
  int i = blockIdx.x * 256 + threadIdx.x;
  if (i >= n4) return;
  if (flags[1]) {
    float4v v = ((const float4v*)x)[i];
    ull w = (ull)f2bf(v.x) | ((ull)f2bf(v.y) << 16) | ((ull)f2bf(v.z) << 32) |
            ((ull)f2bf(v.w) << 48);
    ((ull*)xc)[i] = w;
  } else {
    ((ull*)xc)[i] = ((const ull*)x)[i];
  }
}

// One wave per node, width 128 (bf16 in):
//   out[d] = dinv[d]*(dinv[d]*V[d] + sum_{s in CSR[d]} dinv[s]*V[s]) [+ bias]
template <bool BIAS, bool OUTF32>
__global__ __launch_bounds__(256) void agg_kernel(
    const unsigned short* __restrict__ V, const int* __restrict__ off,
    const int* __restrict__ csr, const float* __restrict__ dinv,
    const unsigned short* __restrict__ bias, void* __restrict__ outv) {
  int d = (blockIdx.x * 256 + threadIdx.x) >> 6;
  int lane = threadIdx.x & 63;
  if (d >= N_NODES) return;
  float dv = dinv[d];
  unsigned int w0 = *(const unsigned int*)(V + (size_t)d * 128 + lane * 2);
  float a0 = dv * bf2f((unsigned short)w0);
  float a1 = dv * bf2f((unsigned short)(w0 >> 16));
  int e1 = off[d + 1];
  for (int e = off[d]; e < e1; ++e) {
    int s = csr[e];
    float ds = dinv[s];
    unsigned int w = *(const unsigned int*)(V + (size_t)s * 128 + lane * 2);
    a0 = fmaf(ds, bf2f((unsigned short)w), a0);
    a1 = fmaf(ds, bf2f((unsigned short)(w >> 16)), a1);
  }
  a0 *= dv; a1 *= dv;
  if (BIAS) {
    a0 += bf2f(bias[lane * 2]);
    a1 += bf2f(bias[lane * 2 + 1]);
  }
  size_t idx = (size_t)d * 128 + lane * 2;
  if (OUTF32) {
    float* of = (float*)outv;
    of[idx] = a0;
    of[idx + 1] = a1;
  } else {
    unsigned int wo = (unsigned int)f2bf(a0) | ((unsigned int)f2bf(a1) << 16);
    *(unsigned int*)((unsigned short*)outv + idx) = wo;
  }
}

// Fused per 64-row tile, in place: xg <- relu(xg@W1 + b1) @ W2 (MFMA).
// Correctness evidence: R4 (this kernel) and R5 (scalar VALU GEMM) produced
// bit-identical outputs. Each block owns its 64 rows; in-place is race-free.
__global__ __launch_bounds__(256) void fused_kernel(
    unsigned short* __restrict__ xg, const unsigned short* __restrict__ Wt1,
    const unsigned short* __restrict__ b1, const unsigned short* __restrict__ Wt2,
    int M) {
  __shared__ unsigned short hh[64 * HPAD];  // 33792 B
  int wid = threadIdx.x >> 6, lane = threadIdx.x & 63;
  int ml = lane & 15, q = lane >> 4;
  int m0 = blockIdx.x * 64 + wid * 16;
  int row = m0 + ml;
  if (row >= M) row = M - 1;
  const short* Ar = (const short*)xg + (size_t)row * IN_DIM + q * 8;

  // phase 1: hh = relu(xg_tile @ W1 + b1), 16 col-tiles, K=128
  f32x4 acc1[16] = {};
  #pragma unroll
  for (int k0 = 0; k0 < IN_DIM; k0 += 32) {
    bf16x8 a = *(const bf16x8*)(Ar + k0);
    #pragma unroll
    for (int t = 0; t < 16; ++t) {
      const short* Br = (const short*)Wt1 + (size_t)(t * 16 + ml) * IN_DIM + k0 + q * 8;
      bf16x8 b = *(const bf16x8*)Br;
      acc1[t] = __builtin_amdgcn_mfma_f32_16x16x32_bf16(a, b, acc1[t], 0, 0, 0);
    }
  }
  #pragma unroll
  for (int t = 0; t < 16; ++t) {
    float bv = bf2f(b1[t * 16 + ml]);
    #pragma unroll
    for (int r = 0; r < 4; ++r) {
      int lrow = wid * 16 + q * 4 + r;
      hh[lrow * HPAD + t * 16 + ml] = f2bf(fmaxf(acc1[t][r] + bv, 0.0f));
    }
  }
  __syncthreads();

  // phase 2: xg_tile = hh @ W2, 8 col-tiles, K=256, A from LDS
  f32x4 acc2[8] = {};
  const unsigned short* As = &hh[(size_t)(wid * 16 + ml) * HPAD + q * 8];
  #pragma unroll
  for (int k0 = 0; k0 < HID_DIM; k0 += 32) {
    bf16x8 a = *(const bf16x8*)(As + k0);
    #pragma unroll
    for (int t = 0; t < 8; ++t) {
      const short* Br = (const short*)Wt2 + (size_t)(t * 16 + ml) * HID_DIM + k0 + q * 8;
      bf16x8 b = *(const bf16x8*)Br;
      acc2[t] = __builtin_amdgcn_mfma_f32_16x16x32_bf16(a, b, acc2[t], 0, 0, 0);
    }
  }
  #pragma unroll
  for (int r = 0; r < 4; ++r) {
    int orow = m0 + q * 4 + r;
    if (orow < M) {
      #pragma unroll
      for (int t = 0; t < 8; ++t)
        xg[(size_t)orow * OUT_DIM + t * 16 + ml] = f2bf(acc2[t][r]);
    }
  }
}

extern "C" void kernel_launch(void* const* d_in, const int* in_sizes, int n_in,
                              void* d_out, int out_size, void* d_ws, size_t ws_size,
                              hipStream_t stream) {
  const void* x  = d_in[0];
  const int*  ei = (const int*)d_in[1];
  const void* W1 = d_in[2];
  const void* b1 = d_in[3];
  const void* W2 = d_in[4];
  const void* b2 = d_in[5];

  // Workspace carve — ~59.4 MB (proven to fit in R6)
  char* wsb = (char*)d_ws;
  size_t o = 0;
  auto carve = [&](size_t bytes) {
    o = (o + 511) & ~(size_t)511;
    void* p = wsb + o;
    o += bytes;
    return p;
  };
  int*   flags = (int*)carve(8);
  int*   deg  = (int*)carve((size_t)N_NODES * 4);
  int*   off  = (int*)carve((size_t)(N_NODES + 1) * 4);
  int*   cur  = (int*)carve((size_t)N_NODES * 4);
  float* dinv = (float*)carve((size_t)N_NODES * 4);
  int*   csr  = (int*)carve((size_t)N_EDGES * 4);
  int*   bsum = (int*)carve((size_t)NB * 4);
  int*   boff = (int*)carve((size_t)NB * 4);
  unsigned short* Wt1 = (unsigned short*)carve((size_t)IN_DIM * HID_DIM * 2);   // [256][128]
  unsigned short* Wt2 = (unsigned short*)carve((size_t)HID_DIM * OUT_DIM * 2);  // [128][256]
  unsigned short* b1c = (unsigned short*)carve((size_t)HID_DIM * 2);
  unsigned short* b2c = (unsigned short*)carve((size_t)OUT_DIM * 2);
  unsigned short* xc  = (unsigned short*)carve((size_t)N_NODES * 128 * 2);  // bf16 x
  unsigned short* xa  = (unsigned short*)carve((size_t)N_NODES * 128 * 2);  // Ahat@x, then layer-2 input

  detect_kernel<<<1, 64, 0, stream>>>(ei, (const unsigned int*)x, flags);
  zero_kernel<<<(N_NODES + 255) / 256, 256, 0, stream>>>(deg, N_NODES);
  count_kernel<<<(N_EDGES + 255) / 256, 256, 0, stream>>>(ei, flags, deg);
  bsum_kernel<<<NB, 1024, 0, stream>>>(deg, bsum, N_NODES);
  bscan_kernel<<<1, 64, 0, stream>>>(bsum, boff, off + N_NODES, NB);
  bfill_kernel<<<NB, 1024, 0, stream>>>(deg, boff, off, cur, dinv, N_NODES);
  fill_kernel<<<(N_EDGES + 255) / 256, 256, 0, stream>>>(ei, flags, cur, csr);
  transpose_kernel<<<(IN_DIM * HID_DIM + 255) / 256, 256, 0, stream>>>(W1, flags, Wt1, IN_DIM, HID_DIM);
  transpose_kernel<<<(HID_DIM * OUT_DIM + 255) / 256, 256, 0, stream>>>(W2, flags, Wt2, HID_DIM, OUT_DIM);
  convb_kernel<<<1, 256, 0, stream>>>(b1, flags, b1c, HID_DIM);
  convb_kernel<<<1, 256, 0, stream>>>(b2, flags, b2c, OUT_DIM);
  int n4 = N_NODES * IN_DIM / 4;
  convx_kernel<<<(n4 + 255) / 256, 256, 0, stream>>>(x, flags, xc, n4);

  // xa = Ahat @ x (bf16 gather from 25.6 MB xc)
  agg_kernel<false, false>
      <<<(N_NODES * 64) / 256, 256, 0, stream>>>(xc, off, csr, dinv, nullptr, xa);
  // xa = relu(xa @ W1 + b1) @ W2   (in place, MFMA)
  fused_kernel<<<(N_NODES + 63) / 64, 256, 0, stream>>>(xa, Wt1, b1c, Wt2, N_NODES);
  // out = Ahat @ xa + b2  (fp32 store to d_out)
  agg_kernel<true, true>
      <<<(N_NODES * 64) / 256, 256, 0, stream>>>(xa, off, csr, dinv, b2c, d_out);
}

// Round 8
// 579.145 us; speedup vs baseline: 2.9763x; 1.2910x over previous
//
#include <hip/hip_runtime.h>
#include <hip/hip_bf16.h>

#define N_NODES 100000
#define N_EDGES 1600000
#define IN_DIM 128
#define HID_DIM 256
#define OUT_DIM 128
#define HPAD 264  // LDS row stride (elements) for 256-wide hh tile
#define NB ((N_NODES + 1023) / 1024)  // 98 scan blocks

typedef __attribute__((ext_vector_type(8))) short bf16x8;
typedef __attribute__((ext_vector_type(4))) float f32x4;
typedef __attribute__((ext_vector_type(4))) float float4v;
typedef unsigned long long ull;

__device__ __forceinline__ float bf2f(unsigned short u) {
  union { unsigned int i; float f; } c; c.i = ((unsigned int)u) << 16; return c.f;
}
__device__ __forceinline__ unsigned short f2bf(float f) {
  __hip_bfloat16 h = __float2bfloat16(f);
  return *(unsigned short*)&h;
}

__global__ void zero_kernel(int* p, int n) {
  int i = blockIdx.x * 256 + threadIdx.x;
  if (i < n) p[i] = 0;
}

// flags[0] = emode (1 = edge_index int64), flags[1] = fmode (1 = floats fp32).
// Parallelized across one wave (R7 version was 1 thread x 272 serial loads).
__global__ void detect_kernel(const int* __restrict__ ei,
                              const unsigned int* __restrict__ xw,
                              int* __restrict__ flags) {
  int lane = threadIdx.x;  // blockDim = 64
  const long long* p = (const long long*)ei;
  long long v = p[lane & 15];
  int ebad = (lane < 16) && (v < 0 || v >= N_NODES);
  ull ebm = __ballot(ebad);
  int isf32 = 0;
  #pragma unroll
  for (int i = 0; i < 4; ++i) {
    unsigned int ex = (xw[lane * 4 + i] >> 7) & 0xFF;
    if (ex >= 0xC0) isf32 = 1;  // |v| >= 2^65: impossible for real data
  }
  ull fbm = __ballot(isf32);
  if (lane == 0) {
    flags[0] = (ebm == 0) ? 1 : 0;
    flags[1] = (fbm != 0) ? 1 : 0;
  }
}

__device__ __forceinline__ int edge_at(const int* ei, int idx, int mode) {
  return mode ? (int)((const long long*)ei)[idx] : ei[idx];
}

__global__ void count_kernel(const int* __restrict__ ei, const int* __restrict__ flags,
                             int* __restrict__ deg) {
  int e = blockIdx.x * 256 + threadIdx.x;
  if (e >= N_EDGES) return;
  int m = flags[0];
  unsigned d = (unsigned)edge_at(ei, N_EDGES + e, m);
  if (d < N_NODES) atomicAdd(&deg[d], 1);
}

// --- hierarchical scan ---
__global__ __launch_bounds__(1024) void bsum_kernel(const int* __restrict__ deg,
                                                    int* __restrict__ bsum, int n) {
  __shared__ int ws[16];
  int tid = threadIdx.x, lane = tid & 63, wid = tid >> 6;
  int idx = blockIdx.x * 1024 + tid;
  int v = (idx < n) ? deg[idx] : 0;
  #pragma unroll
  for (int o = 32; o > 0; o >>= 1) v += __shfl_down(v, o);
  if (lane == 0) ws[wid] = v;
  __syncthreads();
  if (tid == 0) {
    int r = 0;
    #pragma unroll
    for (int i = 0; i < 16; ++i) r += ws[i];
    bsum[blockIdx.x] = r;
  }
}

__global__ void bscan_kernel(const int* __restrict__ bsum, int* __restrict__ boff,
                             int* __restrict__ total, int nb) {
  int lane = threadIdx.x;  // blockDim = 64
  int carry = 0;
  for (int c = 0; c < (nb + 63) / 64; ++c) {
    int idx = c * 64 + lane;
    int v = (idx < nb) ? bsum[idx] : 0;
    int x = v;
    #pragma unroll
    for (int o = 1; o < 64; o <<= 1) {
      int y = __shfl_up(x, o);
      if (lane >= o) x += y;
    }
    if (idx < nb) boff[idx] = carry + x - v;
    carry += __shfl(x, 63);
  }
  if (lane == 0) *total = carry;
}

__global__ __launch_bounds__(1024) void bfill_kernel(const int* __restrict__ deg,
                                                     const int* __restrict__ boff,
                                                     int* __restrict__ off,
                                                     int* __restrict__ cur,
                                                     float* __restrict__ dinv, int n) {
  __shared__ int wsum[16];
  __shared__ int wpre[16];
  int tid = threadIdx.x, lane = tid & 63, wid = tid >> 6;
  int idx = blockIdx.x * 1024 + tid;
  int v = (idx < n) ? deg[idx] : 0;
  int x = v;
  #pragma unroll
  for (int o = 1; o < 64; o <<= 1) {
    int y = __shfl_up(x, o);
    if (lane >= o) x += y;
  }
  if (lane == 63) wsum[wid] = x;
  __syncthreads();
  if (tid == 0) {
    int r = 0;
    #pragma unroll
    for (int i = 0; i < 16; ++i) { wpre[i] = r; r += wsum[i]; }
  }
  __syncthreads();
  int excl = boff[blockIdx.x] + wpre[wid] + x - v;
  if (idx < n) {
    off[idx] = excl;
    cur[idx] = excl;
    dinv[idx] = rsqrtf((float)(v + 1));  // +1 self-loop
  }
}

__global__ void fill_kernel(const int* __restrict__ ei, const int* __restrict__ flags,
                            int* __restrict__ cur, int* __restrict__ csr) {
  int e = blockIdx.x * 256 + threadIdx.x;
  if (e >= N_EDGES) return;
  int m = flags[0];
  int s = edge_at(ei, e, m);
  unsigned d = (unsigned)edge_at(ei, N_EDGES + e, m);
  if (d < N_NODES) {
    int p = atomicAdd(&cur[d], 1);
    if ((unsigned)p < N_EDGES) csr[p] = s;
  }
}

// W:[K][N] (fp32 or bf16 per fmode) -> Wt:[N][K] bf16.
__global__ void transpose_kernel(const void* __restrict__ W, const int* __restrict__ flags,
                                 unsigned short* __restrict__ Wt, int K, int N) {
  int i = blockIdx.x * 256 + threadIdx.x;
  if (i >= K * N) return;
  int k = i / N, n = i % N;
  unsigned short v = flags[1] ? f2bf(((const float*)W)[i]) : ((const unsigned short*)W)[i];
  Wt[n * K + k] = v;
}

__global__ void convb_kernel(const void* __restrict__ b, const int* __restrict__ flags,
                             unsigned short* __restrict__ bc, int n) {
  int i = blockIdx.x * 256 + threadIdx.x;
  if (i >= n) return;
  bc[i] = flags[1] ? f2bf(((const float*)b)[i]) : ((const unsigned short*)b)[i];
}

// x (fp32 or bf16) -> xc bf16, 4 elem/thread.
__global__ void convx_kernel(const void* __restrict__ x, const int* __restrict__ flags,
                             unsigned short* __restrict__ xc, int n4) {
  int i = blockIdx.x * 256 + threadIdx.x;
  if (i >= n4) return;
  if (flags[1]) {
    float4v v = ((const float4v*)x)[i];
    ull w = (ull)f2bf(v.x) | ((ull)f2bf(v.y) << 16) | ((ull)f2bf(v.z) << 32) |
            ((ull)f2bf(v.w) << 48);
    ((ull*)xc)[i] = w;
  } else {
    ((ull*)xc)[i] = ((const ull*)x)[i];
  }
}

// One wave per node, width 128 (bf16 in):
//   out[d] = dinv[d]*(dinv[d]*V[d] + sum_{s in CSR[d]} dinv[s]*V[s]) [+ bias]
// Edge loop unrolled x8: R7 was latency-bound (VALUBusy 19%, 1.6 TB/s) with one
// dependent 256 B row-load in flight; x8 gives 8 independent loads per level.
template <bool BIAS, bool OUTF32>
__global__ __launch_bounds__(256) void agg_kernel(
    const unsigned short* __restrict__ V, const int* __restrict__ off,
    const int* __restrict__ csr, const float* __restrict__ dinv,
    const unsigned short* __restrict__ bias, void* __restrict__ outv) {
  int d = (blockIdx.x * 256 + threadIdx.x) >> 6;
  int lane = threadIdx.x & 63;
  if (d >= N_NODES) return;
  const unsigned short* Vl = V + lane * 2;
  float dv = dinv[d];
  unsigned int w0 = *(const unsigned int*)(Vl + (size_t)d * 128);
  float a0 = dv * bf2f((unsigned short)w0);
  float a1 = dv * bf2f((unsigned short)(w0 >> 16));
  int e = off[d], e1 = off[d + 1];
  for (; e + 8 <= e1; e += 8) {
    int s[8];
    #pragma unroll
    for (int j = 0; j < 8; ++j) s[j] = csr[e + j];
    float ds[8];
    unsigned int w[8];
    #pragma unroll
    for (int j = 0; j < 8; ++j) ds[j] = dinv[s[j]];
    #pragma unroll
    for (int j = 0; j < 8; ++j) w[j] = *(const unsigned int*)(Vl + (size_t)s[j] * 128);
    #pragma unroll
    for (int j = 0; j < 8; ++j) {
      a0 = fmaf(ds[j], bf2f((unsigned short)w[j]), a0);
      a1 = fmaf(ds[j], bf2f((unsigned short)(w[j] >> 16)), a1);
    }
  }
  for (; e < e1; ++e) {
    int s = csr[e];
    float ds = dinv[s];
    unsigned int w = *(const unsigned int*)(Vl + (size_t)s * 128);
    a0 = fmaf(ds, bf2f((unsigned short)w), a0);
    a1 = fmaf(ds, bf2f((unsigned short)(w >> 16)), a1);
  }
  a0 *= dv; a1 *= dv;
  if (BIAS) {
    a0 += bf2f(bias[lane * 2]);
    a1 += bf2f(bias[lane * 2 + 1]);
  }
  size_t idx = (size_t)d * 128 + lane * 2;
  if (OUTF32) {
    float* of = (float*)outv;
    of[idx] = a0;
    of[idx + 1] = a1;
  } else {
    unsigned int wo = (unsigned int)f2bf(a0) | ((unsigned int)f2bf(a1) << 16);
    *(unsigned int*)((unsigned short*)outv + idx) = wo;
  }
}

// Fused per 64-row tile, in place: xg <- relu(xg@W1 + b1) @ W2 (MFMA).
__global__ __launch_bounds__(256) void fused_kernel(
    unsigned short* __restrict__ xg, const unsigned short* __restrict__ Wt1,
    const unsigned short* __restrict__ b1, const unsigned short* __restrict__ Wt2,
    int M) {
  __shared__ unsigned short hh[64 * HPAD];  // 33792 B
  int wid = threadIdx.x >> 6, lane = threadIdx.x & 63;
  int ml = lane & 15, q = lane >> 4;
  int m0 = blockIdx.x * 64 + wid * 16;
  int row = m0 + ml;
  if (row >= M) row = M - 1;
  const short* Ar = (const short*)xg + (size_t)row * IN_DIM + q * 8;

  // phase 1: hh = relu(xg_tile @ W1 + b1), 16 col-tiles, K=128
  f32x4 acc1[16] = {};
  #pragma unroll
  for (int k0 = 0; k0 < IN_DIM; k0 += 32) {
    bf16x8 a = *(const bf16x8*)(Ar + k0);
    #pragma unroll
    for (int t = 0; t < 16; ++t) {
      const short* Br = (const short*)Wt1 + (size_t)(t * 16 + ml) * IN_DIM + k0 + q * 8;
      bf16x8 b = *(const bf16x8*)Br;
      acc1[t] = __builtin_amdgcn_mfma_f32_16x16x32_bf16(a, b, acc1[t], 0, 0, 0);
    }
  }
  #pragma unroll
  for (int t = 0; t < 16; ++t) {
    float bv = bf2f(b1[t * 16 + ml]);
    #pragma unroll
    for (int r = 0; r < 4; ++r) {
      int lrow = wid * 16 + q * 4 + r;
      hh[lrow * HPAD + t * 16 + ml] = f2bf(fmaxf(acc1[t][r] + bv, 0.0f));
    }
  }
  __syncthreads();

  // phase 2: xg_tile = hh @ W2, 8 col-tiles, K=256, A from LDS
  f32x4 acc2[8] = {};
  const unsigned short* As = &hh[(size_t)(wid * 16 + ml) * HPAD + q * 8];
  #pragma unroll
  for (int k0 = 0; k0 < HID_DIM; k0 += 32) {
    bf16x8 a = *(const bf16x8*)(As + k0);
    #pragma unroll
    for (int t = 0; t < 8; ++t) {
      const short* Br = (const short*)Wt2 + (size_t)(t * 16 + ml) * HID_DIM + k0 + q * 8;
      bf16x8 b = *(const bf16x8*)Br;
      acc2[t] = __builtin_amdgcn_mfma_f32_16x16x32_bf16(a, b, acc2[t], 0, 0, 0);
    }
  }
  #pragma unroll
  for (int r = 0; r < 4; ++r) {
    int orow = m0 + q * 4 + r;
    if (orow < M) {
      #pragma unroll
      for (int t = 0; t < 8; ++t)
        xg[(size_t)orow * OUT_DIM + t * 16 + ml] = f2bf(acc2[t][r]);
    }
  }
}

extern "C" void kernel_launch(void* const* d_in, const int* in_sizes, int n_in,
                              void* d_out, int out_size, void* d_ws, size_t ws_size,
                              hipStream_t stream) {
  const void* x  = d_in[0];
  const int*  ei = (const int*)d_in[1];
  const void* W1 = d_in[2];
  const void* b1 = d_in[3];
  const void* W2 = d_in[4];
  const void* b2 = d_in[5];

  // Workspace carve — ~59.4 MB (proven to fit)
  char* wsb = (char*)d_ws;
  size_t o = 0;
  auto carve = [&](size_t bytes) {
    o = (o + 511) & ~(size_t)511;
    void* p = wsb + o;
    o += bytes;
    return p;
  };
  int*   flags = (int*)carve(8);
  int*   deg  = (int*)carve((size_t)N_NODES * 4);
  int*   off  = (int*)carve((size_t)(N_NODES + 1) * 4);
  int*   cur  = (int*)carve((size_t)N_NODES * 4);
  float* dinv = (float*)carve((size_t)N_NODES * 4);
  int*   csr  = (int*)carve((size_t)N_EDGES * 4);
  int*   bsum = (int*)carve((size_t)NB * 4);
  int*   boff = (int*)carve((size_t)NB * 4);
  unsigned short* Wt1 = (unsigned short*)carve((size_t)IN_DIM * HID_DIM * 2);   // [256][128]
  unsigned short* Wt2 = (unsigned short*)carve((size_t)HID_DIM * OUT_DIM * 2);  // [128][256]
  unsigned short* b1c = (unsigned short*)carve((size_t)HID_DIM * 2);
  unsigned short* b2c = (unsigned short*)carve((size_t)OUT_DIM * 2);
  unsigned short* xc  = (unsigned short*)carve((size_t)N_NODES * 128 * 2);  // bf16 x
  unsigned short* xa  = (unsigned short*)carve((size_t)N_NODES * 128 * 2);  // Ahat@x -> layer-2 in

  detect_kernel<<<1, 64, 0, stream>>>(ei, (const unsigned int*)x, flags);
  zero_kernel<<<(N_NODES + 255) / 256, 256, 0, stream>>>(deg, N_NODES);
  count_kernel<<<(N_EDGES + 255) / 256, 256, 0, stream>>>(ei, flags, deg);
  bsum_kernel<<<NB, 1024, 0, stream>>>(deg, bsum, N_NODES);
  bscan_kernel<<<1, 64, 0, stream>>>(bsum, boff, off + N_NODES, NB);
  bfill_kernel<<<NB, 1024, 0, stream>>>(deg, boff, off, cur, dinv, N_NODES);
  fill_kernel<<<(N_EDGES + 255) / 256, 256, 0, stream>>>(ei, flags, cur, csr);
  transpose_kernel<<<(IN_DIM * HID_DIM + 255) / 256, 256, 0, stream>>>(W1, flags, Wt1, IN_DIM, HID_DIM);
  transpose_kernel<<<(HID_DIM * OUT_DIM + 255) / 256, 256, 0, stream>>>(W2, flags, Wt2, HID_DIM, OUT_DIM);
  convb_kernel<<<1, 256, 0, stream>>>(b1, flags, b1c, HID_DIM);
  convb_kernel<<<1, 256, 0, stream>>>(b2, flags, b2c, OUT_DIM);
  int n4 = N_NODES * IN_DIM / 4;
  convx_kernel<<<(n4 + 255) / 256, 256, 0, stream>>>(x, flags, xc, n4);

  // xa = Ahat @ x (bf16 gather from 25.6 MB xc)
  agg_kernel<false, false>
      <<<(N_NODES * 64) / 256, 256, 0, stream>>>(xc, off, csr, dinv, nullptr, xa);
  // xa = relu(xa @ W1 + b1) @ W2   (in place, MFMA)
  fused_kernel<<<(N_NODES + 63) / 64, 256, 0, stream>>>(xa, Wt1, b1c, Wt2, N_NODES);
  // out = Ahat @ xa + b2  (fp32 store to d_out)
  agg_kernel<true, true>
      <<<(N_NODES * 64) / 256, 256, 0, stream>>>(xa, off, csr, dinv, b2c, d_out);
}

// Round 9
// 520.231 us; speedup vs baseline: 3.3133x; 1.1132x over previous
//
#include <hip/hip_runtime.h>
#include <hip/hip_bf16.h>

#define N_NODES 100000
#define N_EDGES 1600000
#define IN_DIM 128
#define HID_DIM 256
#define OUT_DIM 128
#define HPAD 264  // LDS row stride (elements) for 256-wide hh tile
#define NB ((N_NODES + 1023) / 1024)  // 98 scan blocks
#define DCHUNK 12500                  // N_NODES / 8 dst-range per XCD-group
#define EGRID 1024                    // sliced-kernel grid: 128 edge-slices x 8 XCD groups

typedef __attribute__((ext_vector_type(8))) short bf16x8;
typedef __attribute__((ext_vector_type(4))) float f32x4;
typedef __attribute__((ext_vector_type(4))) float float4v;
typedef unsigned long long ull;

__device__ __forceinline__ float bf2f(unsigned short u) {
  union { unsigned int i; float f; } c; c.i = ((unsigned int)u) << 16; return c.f;
}
__device__ __forceinline__ unsigned short f2bf(float f) {
  __hip_bfloat16 h = __float2bfloat16(f);
  return *(unsigned short*)&h;
}

__global__ void zero_kernel(int* p, int n) {
  int i = blockIdx.x * 256 + threadIdx.x;
  if (i < n) p[i] = 0;
}

// flags[0] = emode (1 = edge_index int64), flags[1] = fmode (1 = floats fp32).
__global__ void detect_kernel(const int* __restrict__ ei,
                              const unsigned int* __restrict__ xw,
                              int* __restrict__ flags) {
  int lane = threadIdx.x;  // blockDim = 64
  const long long* p = (const long long*)ei;
  long long v = p[lane & 15];
  int ebad = (lane < 16) && (v < 0 || v >= N_NODES);
  ull ebm = __ballot(ebad);
  int isf32 = 0;
  #pragma unroll
  for (int i = 0; i < 4; ++i) {
    unsigned int ex = (xw[lane * 4 + i] >> 7) & 0xFF;
    if (ex >= 0xC0) isf32 = 1;  // |v| >= 2^65: impossible for real data
  }
  ull fbm = __ballot(isf32);
  if (lane == 0) {
    flags[0] = (ebm == 0) ? 1 : 0;
    flags[1] = (fbm != 0) ? 1 : 0;
  }
}

__device__ __forceinline__ int edge_at(const int* ei, int idx, int mode) {
  return mode ? (int)((const long long*)ei)[idx] : ei[idx];
}

// XCD-sliced count: block b handles dst-range (b&7); deg lines + atomics stay
// in one XCD's L2. Each group re-reads the dst column (LLC-resident, 25.6 MB).
__global__ void count_kernel(const int* __restrict__ ei, const int* __restrict__ flags,
                             int* __restrict__ deg) {
  int g = blockIdx.x & 7;
  unsigned lo = (unsigned)(g * DCHUNK);
  unsigned hi = lo + DCHUNK; if (hi > N_NODES) hi = N_NODES;
  int m = flags[0];
  int stride = (EGRID >> 3) * 256;
  for (int e = (blockIdx.x >> 3) * 256 + threadIdx.x; e < N_EDGES; e += stride) {
    unsigned d = (unsigned)edge_at(ei, N_EDGES + e, m);
    if (d >= lo && d < hi) atomicAdd(&deg[d], 1);
  }
}

// --- hierarchical scan ---
__global__ __launch_bounds__(1024) void bsum_kernel(const int* __restrict__ deg,
                                                    int* __restrict__ bsum, int n) {
  __shared__ int ws[16];
  int tid = threadIdx.x, lane = tid & 63, wid = tid >> 6;
  int idx = blockIdx.x * 1024 + tid;
  int v = (idx < n) ? deg[idx] : 0;
  #pragma unroll
  for (int o = 32; o > 0; o >>= 1) v += __shfl_down(v, o);
  if (lane == 0) ws[wid] = v;
  __syncthreads();
  if (tid == 0) {
    int r = 0;
    #pragma unroll
    for (int i = 0; i < 16; ++i) r += ws[i];
    bsum[blockIdx.x] = r;
  }
}

__global__ void bscan_kernel(const int* __restrict__ bsum, int* __restrict__ boff,
                             int* __restrict__ total, int nb) {
  int lane = threadIdx.x;  // blockDim = 64
  int carry = 0;
  for (int c = 0; c < (nb + 63) / 64; ++c) {
    int idx = c * 64 + lane;
    int v = (idx < nb) ? bsum[idx] : 0;
    int x = v;
    #pragma unroll
    for (int o = 1; o < 64; o <<= 1) {
      int y = __shfl_up(x, o);
      if (lane >= o) x += y;
    }
    if (idx < nb) boff[idx] = carry + x - v;
    carry += __shfl(x, 63);
  }
  if (lane == 0) *total = carry;
}

__global__ __launch_bounds__(1024) void bfill_kernel(const int* __restrict__ deg,
                                                     const int* __restrict__ boff,
                                                     int* __restrict__ off,
                                                     int* __restrict__ cur,
                                                     float* __restrict__ dinv, int n) {
  __shared__ int wsum[16];
  __shared__ int wpre[16];
  int tid = threadIdx.x, lane = tid & 63, wid = tid >> 6;
  int idx = blockIdx.x * 1024 + tid;
  int v = (idx < n) ? deg[idx] : 0;
  int x = v;
  #pragma unroll
  for (int o = 1; o < 64; o <<= 1) {
    int y = __shfl_up(x, o);
    if (lane >= o) x += y;
  }
  if (lane == 63) wsum[wid] = x;
  __syncthreads();
  if (tid == 0) {
    int r = 0;
    #pragma unroll
    for (int i = 0; i < 16; ++i) { wpre[i] = r; r += wsum[i]; }
  }
  __syncthreads();
  int excl = boff[blockIdx.x] + wpre[wid] + x - v;
  if (idx < n) {
    off[idx] = excl;
    cur[idx] = excl;
    dinv[idx] = rsqrtf((float)(v + 1));  // +1 self-loop
  }
}

// XCD-sliced fill: same slicing as count. csr slot region per dst-range is a
// contiguous ~0.8 MB window written only by one XCD-group -> full lines
// accumulate in its L2 (R8: 105.9 MB WRITE_SIZE from cross-XCD partial lines).
__global__ void fill_kernel(const int* __restrict__ ei, const int* __restrict__ flags,
                            int* __restrict__ cur, int* __restrict__ csr) {
  int g = blockIdx.x & 7;
  unsigned lo = (unsigned)(g * DCHUNK);
  unsigned hi = lo + DCHUNK; if (hi > N_NODES) hi = N_NODES;
  int m = flags[0];
  int stride = (EGRID >> 3) * 256;
  for (int e = (blockIdx.x >> 3) * 256 + threadIdx.x; e < N_EDGES; e += stride) {
    unsigned d = (unsigned)edge_at(ei, N_EDGES + e, m);
    if (d >= lo && d < hi) {
      int s = edge_at(ei, e, m);
      int p = atomicAdd(&cur[d], 1);
      if ((unsigned)p < N_EDGES) csr[p] = s;
    }
  }
}

// Fused weight prep: Wt1[n][k]=W1[k][n], Wt2[n][k]=W2[k][n], b1c, b2c (bf16).
__global__ void prep_kernel(const void* __restrict__ W1, const void* __restrict__ b1,
                            const void* __restrict__ W2, const void* __restrict__ b2,
                            const int* __restrict__ flags,
                            unsigned short* __restrict__ Wt1, unsigned short* __restrict__ Wt2,
                            unsigned short* __restrict__ b1c, unsigned short* __restrict__ b2c) {
  int i = blockIdx.x * 256 + threadIdx.x;
  int f = flags[1];
  auto cvt = [&](const void* P, int idx) -> unsigned short {
    return f ? f2bf(((const float*)P)[idx]) : ((const unsigned short*)P)[idx];
  };
  if (i < 32768) {                     // W1: [128][256] -> Wt1 [256][128]
    int k = i >> 8, n = i & 255;
    Wt1[n * 128 + k] = cvt(W1, i);
  } else if (i < 65536) {              // W2: [256][128] -> Wt2 [128][256]
    int j = i - 32768;
    int k = j >> 7, n = j & 127;
    Wt2[n * 256 + k] = cvt(W2, j);
  } else if (i < 65792) {
    b1c[i - 65536] = cvt(b1, i - 65536);
  } else if (i < 65920) {
    b2c[i - 65792] = cvt(b2, i - 65792);
  }
}

// x (fp32 or bf16) -> xc bf16, 4 elem/thread.
__global__ void convx_kernel(const void* __restrict__ x, const int* __restrict__ flags,
                             unsigned short* __restrict__ xc, int n4) {
  int i = blockIdx.x * 256 + threadIdx.x;
  if (i >= n4) return;
  if (flags[1]) {
    float4v v = ((const float4v*)x)[i];
    ull w = (ull)f2bf(v.x) | ((ull)f2bf(v.y) << 16) | ((ull)f2bf(v.z) << 32) |
            ((ull)f2bf(v.w) << 48);
    ((ull*)xc)[i] = w;
  } else {
    ((ull*)xc)[i] = ((const ull*)x)[i];
  }
}

// One wave per node, width 128 (bf16 in); edge loop unrolled x8 for MLP.
//   out[d] = dinv[d]*(dinv[d]*V[d] + sum_{s in CSR[d]} dinv[s]*V[s]) [+ bias]
template <bool BIAS, bool OUTF32>
__global__ __launch_bounds__(256) void agg_kernel(
    const unsigned short* __restrict__ V, const int* __restrict__ off,
    const int* __restrict__ csr, const float* __restrict__ dinv,
    const unsigned short* __restrict__ bias, void* __restrict__ outv) {
  int d = (blockIdx.x * 256 + threadIdx.x) >> 6;
  int lane = threadIdx.x & 63;
  if (d >= N_NODES) return;
  const unsigned short* Vl = V + lane * 2;
  float dv = dinv[d];
  unsigned int w0 = *(const unsigned int*)(Vl + (size_t)d * 128);
  float a0 = dv * bf2f((unsigned short)w0);
  float a1 = dv * bf2f((unsigned short)(w0 >> 16));
  int e = off[d], e1 = off[d + 1];
  for (; e + 8 <= e1; e += 8) {
    int s[8];
    #pragma unroll
    for (int j = 0; j < 8; ++j) s[j] = csr[e + j];
    float ds[8];
    unsigned int w[8];
    #pragma unroll
    for (int j = 0; j < 8; ++j) ds[j] = dinv[s[j]];
    #pragma unroll
    for (int j = 0; j < 8; ++j) w[j] = *(const unsigned int*)(Vl + (size_t)s[j] * 128);
    #pragma unroll
    for (int j = 0; j < 8; ++j) {
      a0 = fmaf(ds[j], bf2f((unsigned short)w[j]), a0);
      a1 = fmaf(ds[j], bf2f((unsigned short)(w[j] >> 16)), a1);
    }
  }
  for (; e < e1; ++e) {
    int s = csr[e];
    float ds = dinv[s];
    unsigned int w = *(const unsigned int*)(Vl + (size_t)s * 128);
    a0 = fmaf(ds, bf2f((unsigned short)w), a0);
    a1 = fmaf(ds, bf2f((unsigned short)(w >> 16)), a1);
  }
  a0 *= dv; a1 *= dv;
  if (BIAS) {
    a0 += bf2f(bias[lane * 2]);
    a1 += bf2f(bias[lane * 2 + 1]);
  }
  size_t idx = (size_t)d * 128 + lane * 2;
  if (OUTF32) {
    float* of = (float*)outv;
    of[idx] = a0;
    of[idx + 1] = a1;
  } else {
    unsigned int wo = (unsigned int)f2bf(a0) | ((unsigned int)f2bf(a1) << 16);
    *(unsigned int*)((unsigned short*)outv + idx) = wo;
  }
}

// Fused per 64-row tile, in place: xg <- relu(xg@W1 + b1) @ W2 (MFMA).
__global__ __launch_bounds__(256) void fused_kernel(
    unsigned short* __restrict__ xg, const unsigned short* __restrict__ Wt1,
    const unsigned short* __restrict__ b1, const unsigned short* __restrict__ Wt2,
    int M) {
  __shared__ unsigned short hh[64 * HPAD];  // 33792 B
  int wid = threadIdx.x >> 6, lane = threadIdx.x & 63;
  int ml = lane & 15, q = lane >> 4;
  int m0 = blockIdx.x * 64 + wid * 16;
  int row = m0 + ml;
  if (row >= M) row = M - 1;
  const short* Ar = (const short*)xg + (size_t)row * IN_DIM + q * 8;

  // phase 1: hh = relu(xg_tile @ W1 + b1), 16 col-tiles, K=128
  f32x4 acc1[16] = {};
  #pragma unroll
  for (int k0 = 0; k0 < IN_DIM; k0 += 32) {
    bf16x8 a = *(const bf16x8*)(Ar + k0);
    #pragma unroll
    for (int t = 0; t < 16; ++t) {
      const short* Br = (const short*)Wt1 + (size_t)(t * 16 + ml) * IN_DIM + k0 + q * 8;
      bf16x8 b = *(const bf16x8*)Br;
      acc1[t] = __builtin_amdgcn_mfma_f32_16x16x32_bf16(a, b, acc1[t], 0, 0, 0);
    }
  }
  #pragma unroll
  for (int t = 0; t < 16; ++t) {
    float bv = bf2f(b1[t * 16 + ml]);
    #pragma unroll
    for (int r = 0; r < 4; ++r) {
      int lrow = wid * 16 + q * 4 + r;
      hh[lrow * HPAD + t * 16 + ml] = f2bf(fmaxf(acc1[t][r] + bv, 0.0f));
    }
  }
  __syncthreads();

  // phase 2: xg_tile = hh @ W2, 8 col-tiles, K=256, A from LDS
  f32x4 acc2[8] = {};
  const unsigned short* As = &hh[(size_t)(wid * 16 + ml) * HPAD + q * 8];
  #pragma unroll
  for (int k0 = 0; k0 < HID_DIM; k0 += 32) {
    bf16x8 a = *(const bf16x8*)(As + k0);
    #pragma unroll
    for (int t = 0; t < 8; ++t) {
      const short* Br = (const short*)Wt2 + (size_t)(t * 16 + ml) * HID_DIM + k0 + q * 8;
      bf16x8 b = *(const bf16x8*)Br;
      acc2[t] = __builtin_amdgcn_mfma_f32_16x16x32_bf16(a, b, acc2[t], 0, 0, 0);
    }
  }
  #pragma unroll
  for (int r = 0; r < 4; ++r) {
    int orow = m0 + q * 4 + r;
    if (orow < M) {
      #pragma unroll
      for (int t = 0; t < 8; ++t)
        xg[(size_t)orow * OUT_DIM + t * 16 + ml] = f2bf(acc2[t][r]);
    }
  }
}

extern "C" void kernel_launch(void* const* d_in, const int* in_sizes, int n_in,
                              void* d_out, int out_size, void* d_ws, size_t ws_size,
                              hipStream_t stream) {
  const void* x  = d_in[0];
  const int*  ei = (const int*)d_in[1];
  const void* W1 = d_in[2];
  const void* b1 = d_in[3];
  const void* W2 = d_in[4];
  const void* b2 = d_in[5];

  // Workspace carve — ~59.4 MB (proven to fit)
  char* wsb = (char*)d_ws;
  size_t o = 0;
  auto carve = [&](size_t bytes) {
    o = (o + 511) & ~(size_t)511;
    void* p = wsb + o;
    o += bytes;
    return p;
  };
  int*   flags = (int*)carve(8);
  int*   deg  = (int*)carve((size_t)N_NODES * 4);
  int*   off  = (int*)carve((size_t)(N_NODES + 1) * 4);
  int*   cur  = (int*)carve((size_t)N_NODES * 4);
  float* dinv = (float*)carve((size_t)N_NODES * 4);
  int*   csr  = (int*)carve((size_t)N_EDGES * 4);
  int*   bsum = (int*)carve((size_t)NB * 4);
  int*   boff = (int*)carve((size_t)NB * 4);
  unsigned short* Wt1 = (unsigned short*)carve((size_t)IN_DIM * HID_DIM * 2);   // [256][128]
  unsigned short* Wt2 = (unsigned short*)carve((size_t)HID_DIM * OUT_DIM * 2);  // [128][256]
  unsigned short* b1c = (unsigned short*)carve((size_t)HID_DIM * 2);
  unsigned short* b2c = (unsigned short*)carve((size_t)OUT_DIM * 2);
  unsigned short* xc  = (unsigned short*)carve((size_t)N_NODES * 128 * 2);  // bf16 x
  unsigned short* xa  = (unsigned short*)carve((size_t)N_NODES * 128 * 2);  // Ahat@x -> layer-2 in

  detect_kernel<<<1, 64, 0, stream>>>(ei, (const unsigned int*)x, flags);
  zero_kernel<<<(N_NODES + 255) / 256, 256, 0, stream>>>(deg, N_NODES);
  count_kernel<<<EGRID, 256, 0, stream>>>(ei, flags, deg);
  bsum_kernel<<<NB, 1024, 0, stream>>>(deg, bsum, N_NODES);
  bscan_kernel<<<1, 64, 0, stream>>>(bsum, boff, off + N_NODES, NB);
  bfill_kernel<<<NB, 1024, 0, stream>>>(deg, boff, off, cur, dinv, N_NODES);
  fill_kernel<<<EGRID, 256, 0, stream>>>(ei, flags, cur, csr);
  prep_kernel<<<258, 256, 0, stream>>>(W1, b1, W2, b2, flags, Wt1, Wt2, b1c, b2c);
  int n4 = N_NODES * IN_DIM / 4;
  convx_kernel<<<(n4 + 255) / 256, 256, 0, stream>>>(x, flags, xc, n4);

  // xa = Ahat @ x (bf16 gather from 25.6 MB xc)
  agg_kernel<false, false>
      <<<(N_NODES * 64) / 256, 256, 0, stream>>>(xc, off, csr, dinv, nullptr, xa);
  // xa = relu(xa @ W1 + b1) @ W2   (in place, MFMA)
  fused_kernel<<<(N_NODES + 63) / 64, 256, 0, stream>>>(xa, Wt1, b1c, Wt2, N_NODES);
  // out = Ahat @ xa + b2  (fp32 store to d_out)
  agg_kernel<true, true>
      <<<(N_NODES * 64) / 256, 256, 0, stream>>>(xa, off, csr, dinv, b2c, d_out);
}

// Round 10
// 451.395 us; speedup vs baseline: 3.8186x; 1.1525x over previous
//
#include <hip/hip_runtime.h>
#include <hip/hip_bf16.h>

#define N_NODES 100000
#define N_EDGES 1600000
#define IN_DIM 128
#define HID_DIM 256
#define OUT_DIM 128
#define NB ((N_NODES + 1023) / 1024)  // 98 scan blocks
#define DCHUNK 12500                  // N_NODES / 8 dst-range per XCD-group
#define EGRID 1024                    // sliced-kernel grid: 128 edge-slices x 8 XCD groups
#define NSTRIP (N_NODES / 16)         // 6250 exact (N_NODES % 16 == 0)
#define GWAVES 2048                   // 512 blocks x 4 waves

typedef __attribute__((ext_vector_type(8))) short bf16x8;
typedef __attribute__((ext_vector_type(4))) float f32x4;
typedef __attribute__((ext_vector_type(4))) float float4v;
typedef unsigned long long ull;
typedef unsigned short u16;

__device__ __forceinline__ float bf2f(u16 u) {
  union { unsigned int i; float f; } c; c.i = ((unsigned int)u) << 16; return c.f;
}
__device__ __forceinline__ u16 f2bf(float f) {
  __hip_bfloat16 h = __float2bfloat16(f);
  return *(u16*)&h;
}

__global__ void zero_kernel(int* p, int n) {
  int i = blockIdx.x * 256 + threadIdx.x;
  if (i < n) p[i] = 0;
}

// flags[0] = emode (1 = edge_index int64), flags[1] = fmode (1 = floats fp32).
__global__ void detect_kernel(const int* __restrict__ ei,
                              const unsigned int* __restrict__ xw,
                              int* __restrict__ flags) {
  int lane = threadIdx.x;  // blockDim = 64
  const long long* p = (const long long*)ei;
  long long v = p[lane & 15];
  int ebad = (lane < 16) && (v < 0 || v >= N_NODES);
  ull ebm = __ballot(ebad);
  int isf32 = 0;
  #pragma unroll
  for (int i = 0; i < 4; ++i) {
    unsigned int ex = (xw[lane * 4 + i] >> 7) & 0xFF;
    if (ex >= 0xC0) isf32 = 1;  // |v| >= 2^65: impossible for real data
  }
  ull fbm = __ballot(isf32);
  if (lane == 0) {
    flags[0] = (ebm == 0) ? 1 : 0;
    flags[1] = (fbm != 0) ? 1 : 0;
  }
}

__device__ __forceinline__ int edge_at(const int* ei, int idx, int mode) {
  return mode ? (int)((const long long*)ei)[idx] : ei[idx];
}

// XCD-sliced count: block b handles dst-range (b&7); deg lines + atomics stay
// in one XCD's L2.
__global__ void count_kernel(const int* __restrict__ ei, const int* __restrict__ flags,
                             int* __restrict__ deg) {
  int g = blockIdx.x & 7;
  unsigned lo = (unsigned)(g * DCHUNK);
  unsigned hi = lo + DCHUNK; if (hi > N_NODES) hi = N_NODES;
  int m = flags[0];
  int stride = (EGRID >> 3) * 256;
  for (int e = (blockIdx.x >> 3) * 256 + threadIdx.x; e < N_EDGES; e += stride) {
    unsigned d = (unsigned)edge_at(ei, N_EDGES + e, m);
    if (d >= lo && d < hi) atomicAdd(&deg[d], 1);
  }
}

// --- hierarchical scan ---
__global__ __launch_bounds__(1024) void bsum_kernel(const int* __restrict__ deg,
                                                    int* __restrict__ bsum, int n) {
  __shared__ int ws[16];
  int tid = threadIdx.x, lane = tid & 63, wid = tid >> 6;
  int idx = blockIdx.x * 1024 + tid;
  int v = (idx < n) ? deg[idx] : 0;
  #pragma unroll
  for (int o = 32; o > 0; o >>= 1) v += __shfl_down(v, o);
  if (lane == 0) ws[wid] = v;
  __syncthreads();
  if (tid == 0) {
    int r = 0;
    #pragma unroll
    for (int i = 0; i < 16; ++i) r += ws[i];
    bsum[blockIdx.x] = r;
  }
}

__global__ void bscan_kernel(const int* __restrict__ bsum, int* __restrict__ boff,
                             int* __restrict__ total, int nb) {
  int lane = threadIdx.x;  // blockDim = 64
  int carry = 0;
  for (int c = 0; c < (nb + 63) / 64; ++c) {
    int idx = c * 64 + lane;
    int v = (idx < nb) ? bsum[idx] : 0;
    int x = v;
    #pragma unroll
    for (int o = 1; o < 64; o <<= 1) {
      int y = __shfl_up(x, o);
      if (lane >= o) x += y;
    }
    if (idx < nb) boff[idx] = carry + x - v;
    carry += __shfl(x, 63);
  }
  if (lane == 0) *total = carry;
}

__global__ __launch_bounds__(1024) void bfill_kernel(const int* __restrict__ deg,
                                                     const int* __restrict__ boff,
                                                     int* __restrict__ off,
                                                     int* __restrict__ cur,
                                                     float* __restrict__ dinv, int n) {
  __shared__ int wsum[16];
  __shared__ int wpre[16];
  int tid = threadIdx.x, lane = tid & 63, wid = tid >> 6;
  int idx = blockIdx.x * 1024 + tid;
  int v = (idx < n) ? deg[idx] : 0;
  int x = v;
  #pragma unroll
  for (int o = 1; o < 64; o <<= 1) {
    int y = __shfl_up(x, o);
    if (lane >= o) x += y;
  }
  if (lane == 63) wsum[wid] = x;
  __syncthreads();
  if (tid == 0) {
    int r = 0;
    #pragma unroll
    for (int i = 0; i < 16; ++i) { wpre[i] = r; r += wsum[i]; }
  }
  __syncthreads();
  int excl = boff[blockIdx.x] + wpre[wid] + x - v;
  if (idx < n) {
    off[idx] = excl;
    cur[idx] = excl;
    dinv[idx] = rsqrtf((float)(v + 1));  // +1 self-loop
  }
}

// XCD-sliced fill (R8: 105.9 MB WRITE_SIZE from cross-XCD partial lines).
__global__ void fill_kernel(const int* __restrict__ ei, const int* __restrict__ flags,
                            int* __restrict__ cur, int* __restrict__ csr) {
  int g = blockIdx.x & 7;
  unsigned lo = (unsigned)(g * DCHUNK);
  unsigned hi = lo + DCHUNK; if (hi > N_NODES) hi = N_NODES;
  int m = flags[0];
  int stride = (EGRID >> 3) * 256;
  for (int e = (blockIdx.x >> 3) * 256 + threadIdx.x; e < N_EDGES; e += stride) {
    unsigned d = (unsigned)edge_at(ei, N_EDGES + e, m);
    if (d >= lo && d < hi) {
      int s = edge_at(ei, e, m);
      int p = atomicAdd(&cur[d], 1);
      if ((unsigned)p < N_EDGES) csr[p] = s;
    }
  }
}

// Fused weight prep: Wt1[n][k]=W1[k][n], Wt2[n][k]=W2[k][n], b1c, b2c (bf16).
__global__ void prep_kernel(const void* __restrict__ W1, const void* __restrict__ b1,
                            const void* __restrict__ W2, const void* __restrict__ b2,
                            const int* __restrict__ flags,
                            u16* __restrict__ Wt1, u16* __restrict__ Wt2,
                            u16* __restrict__ b1c, u16* __restrict__ b2c) {
  int i = blockIdx.x * 256 + threadIdx.x;
  int f = flags[1];
  auto cvt = [&](const void* P, int idx) -> u16 {
    return f ? f2bf(((const float*)P)[idx]) : ((const u16*)P)[idx];
  };
  if (i < 32768) {                     // W1: [128][256] -> Wt1 [256][128]
    int k = i >> 8, n = i & 255;
    Wt1[n * 128 + k] = cvt(W1, i);
  } else if (i < 65536) {              // W2: [256][128] -> Wt2 [128][256]
    int j = i - 32768;
    int k = j >> 7, n = j & 127;
    Wt2[n * 256 + k] = cvt(W2, j);
  } else if (i < 65792) {
    b1c[i - 65536] = cvt(b1, i - 65536);
  } else if (i < 65920) {
    b2c[i - 65792] = cvt(b2, i - 65792);
  }
}

// x (fp32 or bf16) -> xc bf16, 4 elem/thread.
__global__ void convx_kernel(const void* __restrict__ x, const int* __restrict__ flags,
                             u16* __restrict__ xc, int n4) {
  int i = blockIdx.x * 256 + threadIdx.x;
  if (i >= n4) return;
  if (flags[1]) {
    float4v v = ((const float4v*)x)[i];
    ull w = (ull)f2bf(v.x) | ((ull)f2bf(v.y) << 16) | ((ull)f2bf(v.z) << 32) |
            ((ull)f2bf(v.w) << 48);
    ((ull*)xc)[i] = w;
  } else {
    ((ull*)xc)[i] = ((const ull*)x)[i];
  }
}

// One wave per node, width 128 (bf16 in); edge loop unrolled x8 (MLP for latency).
template <bool BIAS, bool OUTF32>
__global__ __launch_bounds__(256) void agg_kernel(
    const u16* __restrict__ V, const int* __restrict__ off,
    const int* __restrict__ csr, const float* __restrict__ dinv,
    const u16* __restrict__ bias, void* __restrict__ outv) {
  int d = (blockIdx.x * 256 + threadIdx.x) >> 6;
  int lane = threadIdx.x & 63;
  if (d >= N_NODES) return;
  const u16* Vl = V + lane * 2;
  float dv = dinv[d];
  unsigned int w0 = *(const unsigned int*)(Vl + (size_t)d * 128);
  float a0 = dv * bf2f((u16)w0);
  float a1 = dv * bf2f((u16)(w0 >> 16));
  int e = off[d], e1 = off[d + 1];
  for (; e + 8 <= e1; e += 8) {
    int s[8];
    #pragma unroll
    for (int j = 0; j < 8; ++j) s[j] = csr[e + j];
    float ds[8];
    unsigned int w[8];
    #pragma unroll
    for (int j = 0; j < 8; ++j) ds[j] = dinv[s[j]];
    #pragma unroll
    for (int j = 0; j < 8; ++j) w[j] = *(const unsigned int*)(Vl + (size_t)s[j] * 128);
    #pragma unroll
    for (int j = 0; j < 8; ++j) {
      a0 = fmaf(ds[j], bf2f((u16)w[j]), a0);
      a1 = fmaf(ds[j], bf2f((u16)(w[j] >> 16)), a1);
    }
  }
  for (; e < e1; ++e) {
    int s = csr[e];
    float ds = dinv[s];
    unsigned int w = *(const unsigned int*)(Vl + (size_t)s * 128);
    a0 = fmaf(ds, bf2f((u16)w), a0);
    a1 = fmaf(ds, bf2f((u16)(w >> 16)), a1);
  }
  a0 *= dv; a1 *= dv;
  if (BIAS) {
    a0 += bf2f(bias[lane * 2]);
    a1 += bf2f(bias[lane * 2 + 1]);
  }
  size_t idx = (size_t)d * 128 + lane * 2;
  if (OUTF32) {
    float* of = (float*)outv;
    of[idx] = a0;
    of[idx + 1] = a1;
  } else {
    unsigned int wo = (unsigned int)f2bf(a0) | ((unsigned int)f2bf(a1) << 16);
    *(unsigned int*)((u16*)outv + idx) = wo;
  }
}

// MLP layer 1: h = relu(xa @ W1 + b1). Wt1 (64 KB) staged in LDS with 16B-block
// XOR swizzle (phys_blk = blk ^ (row&15)) -> wave b128 reads spread over all 32
// banks. 512 blocks x 4 waves; wave handles 16-row strips s, s+2048, ...
// (R9 fused kernel read B-fragments from L2 per-MFMA: load-use serialization,
// 117 us with 4% MfmaUtil.)
__global__ __launch_bounds__(256) void mlp1_kernel(
    const u16* __restrict__ xa, const u16* __restrict__ Wt1,
    const u16* __restrict__ b1, u16* __restrict__ h) {
  __shared__ u16 B[32768];  // 65536 B
  int tid = threadIdx.x;
  #pragma unroll
  for (int j = 0; j < 16; ++j) {
    int i = j * 256 + tid;                         // 16B-block index 0..4095
    int row = i >> 4, blk = i & 15;
    int phys = (row << 4) | (blk ^ (row & 15));
    *(bf16x8*)&B[phys * 8] = *(const bf16x8*)(Wt1 + (size_t)i * 8);
  }
  __syncthreads();
  int wid = tid >> 6, lane = tid & 63, ml = lane & 15, q = lane >> 4;
  for (int s = blockIdx.x * 4 + wid; s < NSTRIP; s += GWAVES) {
    const short* Ar = (const short*)xa + (size_t)(s * 16 + ml) * IN_DIM + q * 8;
    f32x4 acc[16] = {};
    #pragma unroll
    for (int k0 = 0; k0 < IN_DIM; k0 += 32) {
      bf16x8 a = *(const bf16x8*)(Ar + k0);
      int kb = k0 >> 3;
      #pragma unroll
      for (int t = 0; t < 16; ++t) {
        int brow = t * 16 + ml;                    // brow & 15 == ml
        const u16* Bp = &B[(((unsigned)brow << 4) | (unsigned)((kb + q) ^ ml)) * 8];
        acc[t] = __builtin_amdgcn_mfma_f32_16x16x32_bf16(a, *(const bf16x8*)Bp, acc[t], 0, 0, 0);
      }
    }
    size_t hb = (size_t)s * 16 * HID_DIM;
    #pragma unroll
    for (int t = 0; t < 16; ++t) {
      float bv = bf2f(b1[t * 16 + ml]);
      #pragma unroll
      for (int r = 0; r < 4; ++r)
        h[hb + (size_t)(q * 4 + r) * HID_DIM + t * 16 + ml] =
            f2bf(fmaxf(acc[t][r] + bv, 0.0f));
    }
  }
}

// MLP layer 2: xg = h @ W2 (bias added later in agg2). Wt2 (64 KB) in LDS,
// swizzle phys_blk = blk ^ (row&15) over 32 blocks/row.
__global__ __launch_bounds__(256) void mlp2_kernel(
    const u16* __restrict__ h, const u16* __restrict__ Wt2, u16* __restrict__ xg) {
  __shared__ u16 B[32768];  // 65536 B
  int tid = threadIdx.x;
  #pragma unroll
  for (int j = 0; j < 16; ++j) {
    int i = j * 256 + tid;                         // 16B-block index 0..4095
    int row = i >> 5, blk = i & 31;
    int phys = (row << 5) | (blk ^ (row & 15));
    *(bf16x8*)&B[phys * 8] = *(const bf16x8*)(Wt2 + (size_t)i * 8);
  }
  __syncthreads();
  int wid = tid >> 6, lane = tid & 63, ml = lane & 15, q = lane >> 4;
  for (int s = blockIdx.x * 4 + wid; s < NSTRIP; s += GWAVES) {
    const short* Ar = (const short*)h + (size_t)(s * 16 + ml) * HID_DIM + q * 8;
    f32x4 acc[8] = {};
    #pragma unroll
    for (int k0 = 0; k0 < HID_DIM; k0 += 32) {
      bf16x8 a = *(const bf16x8*)(Ar + k0);
      int kb = k0 >> 3;
      #pragma unroll
      for (int t = 0; t < 8; ++t) {
        int brow = t * 16 + ml;                    // brow & 15 == ml
        const u16* Bp = &B[(((unsigned)brow << 5) | (unsigned)((kb + q) ^ ml)) * 8];
        acc[t] = __builtin_amdgcn_mfma_f32_16x16x32_bf16(a, *(const bf16x8*)Bp, acc[t], 0, 0, 0);
      }
    }
    size_t gb = (size_t)s * 16 * OUT_DIM;
    #pragma unroll
    for (int t = 0; t < 8; ++t) {
      #pragma unroll
      for (int r = 0; r < 4; ++r)
        xg[gb + (size_t)(q * 4 + r) * OUT_DIM + t * 16 + ml] = f2bf(acc[t][r]);
    }
  }
}

extern "C" void kernel_launch(void* const* d_in, const int* in_sizes, int n_in,
                              void* d_out, int out_size, void* d_ws, size_t ws_size,
                              hipStream_t stream) {
  const void* x  = d_in[0];
  const int*  ei = (const int*)d_in[1];
  const void* W1 = d_in[2];
  const void* b1 = d_in[3];
  const void* W2 = d_in[4];
  const void* b2 = d_in[5];

  // Workspace carve — ~59.4 MB (proven). h (51.2 MB bf16) lives in d_out until
  // the final agg overwrites d_out with fp32.
  char* wsb = (char*)d_ws;
  size_t o = 0;
  auto carve = [&](size_t bytes) {
    o = (o + 511) & ~(size_t)511;
    void* p = wsb + o;
    o += bytes;
    return p;
  };
  int*   flags = (int*)carve(8);
  int*   deg  = (int*)carve((size_t)N_NODES * 4);
  int*   off  = (int*)carve((size_t)(N_NODES + 1) * 4);
  int*   cur  = (int*)carve((size_t)N_NODES * 4);
  float* dinv = (float*)carve((size_t)N_NODES * 4);
  int*   csr  = (int*)carve((size_t)N_EDGES * 4);
  int*   bsum = (int*)carve((size_t)NB * 4);
  int*   boff = (int*)carve((size_t)NB * 4);
  u16*   Wt1 = (u16*)carve((size_t)IN_DIM * HID_DIM * 2);   // [256][128]
  u16*   Wt2 = (u16*)carve((size_t)HID_DIM * OUT_DIM * 2);  // [128][256]
  u16*   b1c = (u16*)carve((size_t)HID_DIM * 2);
  u16*   b2c = (u16*)carve((size_t)OUT_DIM * 2);
  u16*   xc  = (u16*)carve((size_t)N_NODES * 128 * 2);  // bf16 x
  u16*   xa  = (u16*)carve((size_t)N_NODES * 128 * 2);  // Ahat@x; reused as xg by mlp2
  u16*   h   = (u16*)d_out;                             // [N,256] bf16 scratch in d_out

  detect_kernel<<<1, 64, 0, stream>>>(ei, (const unsigned int*)x, flags);
  zero_kernel<<<(N_NODES + 255) / 256, 256, 0, stream>>>(deg, N_NODES);
  count_kernel<<<EGRID, 256, 0, stream>>>(ei, flags, deg);
  bsum_kernel<<<NB, 1024, 0, stream>>>(deg, bsum, N_NODES);
  bscan_kernel<<<1, 64, 0, stream>>>(bsum, boff, off + N_NODES, NB);
  bfill_kernel<<<NB, 1024, 0, stream>>>(deg, boff, off, cur, dinv, N_NODES);
  fill_kernel<<<EGRID, 256, 0, stream>>>(ei, flags, cur, csr);
  prep_kernel<<<258, 256, 0, stream>>>(W1, b1, W2, b2, flags, Wt1, Wt2, b1c, b2c);
  int n4 = N_NODES * IN_DIM / 4;
  convx_kernel<<<(n4 + 255) / 256, 256, 0, stream>>>(x, flags, xc, n4);

  // xa = Ahat @ x (bf16 gather from 25.6 MB xc)
  agg_kernel<false, false>
      <<<(N_NODES * 64) / 256, 256, 0, stream>>>(xc, off, csr, dinv, nullptr, xa);
  // h(d_out) = relu(xa @ W1 + b1)
  mlp1_kernel<<<512, 256, 0, stream>>>(xa, Wt1, b1c, h);
  // xa <- h @ W2   (xa dead as mlp1 input; reused as xg)
  mlp2_kernel<<<512, 256, 0, stream>>>(h, Wt2, xa);
  // out = Ahat @ xg + b2  (fp32 store overwrites h scratch in d_out)
  agg_kernel<true, true>
      <<<(N_NODES * 64) / 256, 256, 0, stream>>>(xa, off, csr, dinv, b2c, d_out);
}